// Round 7
// baseline (231.899 us; speedup 1.0000x reference)
//
#include <hip/hip_runtime.h>

#define TSEQ 512
#define NB   128
#define CDIM 384
#define HD   64
// 384^-0.5 * log2(e): Q pre-scaled so attention uses exp2 directly
#define QSCALE2 0.07362222569f
#define MBIAS2  11.541560327f          // 8 * log2(e); exact offset, cancels in O/l
#define SCLAMP  26.0f                  // 18 * log2(e)

typedef _Float16 half8  __attribute__((ext_vector_type(8)));
typedef _Float16 half4  __attribute__((ext_vector_type(4)));
typedef float    floatx4 __attribute__((ext_vector_type(4)));

typedef __attribute__((address_space(3))) unsigned int lds_u32;
typedef const __attribute__((address_space(1))) unsigned int g_u32;

__device__ __forceinline__ void load_lds16(const void* g, void* l) {
    __builtin_amdgcn_global_load_lds((g_u32*)g, (lds_u32*)l, 16, 0, 0);
}

// ---------------------------------------------------------------------------
// Kernel B: repack the three 384x64 fp32 weight matrices into Wt[mat*64+n][k]
// fp16 so GEMM B loads are contiguous 16B along k.
// ---------------------------------------------------------------------------
__global__ void prep_w(const float* __restrict__ wq, const float* __restrict__ wk,
                       const float* __restrict__ wv, _Float16* __restrict__ Wt)
{
    int i = blockIdx.x * 256 + threadIdx.x;
    const int per = CDIM * HD;               // 24576
    if (i >= 3 * per) return;
    int mat = i / per;
    int rem = i - mat * per;
    int k = rem / HD;
    int n = rem - k * HD;
    const float* w = (mat == 0) ? wq : ((mat == 1) ? wk : wv);
    Wt[((size_t)mat * HD + n) * CDIM + k] = (_Float16)w[rem];
}

// ---------------------------------------------------------------------------
// Kernel C: fused QKV projection, global_load_lds pipeline, DOUBLE-BUFFERED.
// R6 counters: MfmaUtil 5.6% — per-chunk DMA latency (~900 cyc) fully exposed
// at each barrier. Dbuf: barrier -> issue DMA(c+1) into buf^1 -> compute(buf),
// so the next barrier drains an already-flown transfer. LDS 80 KB, 2 blk/CU.
// ---------------------------------------------------------------------------
__global__ __launch_bounds__(256) void qkv_gemm(
    const float* __restrict__ x, const _Float16* __restrict__ Wt,
    const float* __restrict__ bq, const float* __restrict__ bk,
    const float* __restrict__ bv,
    _Float16* __restrict__ Qw, _Float16* __restrict__ Kw,
    _Float16* __restrict__ Vtw, int b0)
{
    __shared__ __align__(16) float    xs[2][8 * 64 * 8];    // 2 x 16 KB
    __shared__ __align__(16) _Float16 wsb[2][8 * 192 * 8];  // 2 x 24 KB

    const int tid  = threadIdx.x;
    const int wave = tid >> 6;
    const int lane = tid & 63;
    const int l16  = lane & 15;
    const int quad = lane >> 4;

    const int row0 = blockIdx.x * 64;
    const size_t rowg = (size_t)b0 * TSEQ + row0;

    floatx4 acc[12];
#pragma unroll
    for (int i = 0; i < 12; ++i)
#pragma unroll
        for (int r = 0; r < 4; ++r) acc[i][r] = 0.f;

    // ---- stage chunk c into buffer bsel ----
    auto stage = [&](int c, int bsel) {
        const int kk0 = c * 64;
#pragma unroll
        for (int i = 0; i < 4; ++i) {          // x: 16 KB, 4 DMA/wave
            const int I    = wave * 4 + i;
            const int cell = I * 32 + (lane >> 1);
            const int kblk = cell >> 6;
            const int m    = cell & 63;
            const int kin0 = (lane & 1) * 4;
            const float* src = x + (rowg + m) * CDIM + kk0 + kblk * 8 + kin0;
            load_lds16(src, (char*)xs + bsel * 16384 + I * 1024);
        }
#pragma unroll
        for (int i = 0; i < 6; ++i) {          // W: 24 KB, 6 DMA/wave
            const int I2   = wave * 6 + i;
            const int c2   = I2 * 64 + lane;
            const int kblk = c2 / 192;
            const int n    = c2 - kblk * 192;
            const _Float16* src = Wt + (size_t)n * CDIM + kk0 + kblk * 8;
            load_lds16(src, (char*)wsb + bsel * 24576 + I2 * 1024);
        }
    };

    stage(0, 0);
    for (int c = 0; c < 6; ++c) {
        __syncthreads();                        // drains DMA(c)
        if (c < 5) stage(c + 1, (c + 1) & 1);   // flies during compute(c)
        const int bsel = c & 1;
#pragma unroll
        for (int kb2 = 0; kb2 < 2; ++kb2) {
            const int kblk = kb2 * 4 + quad;
            const float* ap = xs[bsel] + ((size_t)kblk * 64 + wave * 16 + l16) * 8;
            floatx4 a0 = *(const floatx4*)ap;
            floatx4 a1 = *(const floatx4*)(ap + 4);
            half8 a;
#pragma unroll
            for (int jj = 0; jj < 8; ++jj)
                a[jj] = (_Float16)(jj < 4 ? a0[jj] : a1[jj - 4]);
            const _Float16* bp = wsb[bsel] + ((size_t)kblk * 192 + l16) * 8;
#pragma unroll
            for (int i = 0; i < 12; ++i) {
                half8 bb = *(const half8*)(bp + i * 128);
                acc[i] = __builtin_amdgcn_mfma_f32_16x16x32_f16(a, bb, acc[i], 0, 0, 0);
            }
        }
    }

    // ---- epilogue: bias + RoPE; Q/K row-major, V transposed (b,d,t) ----
    float bq4[4], bk4[4], bv4[4];
#pragma unroll
    for (int s4 = 0; s4 < 4; ++s4) {
        const int cc = s4 * 16 + l16;
        bq4[s4] = bq[cc]; bk4[s4] = bk[cc]; bv4[s4] = bv[cc];
    }
    const int t00  = (row0 & (TSEQ - 1)) + wave * 16 + quad * 4;
    const int bidx = row0 >> 9;
    const int rowb = row0 + wave * 16 + quad * 4;

#pragma unroll
    for (int r = 0; r < 4; ++r) {
        const int t = t00 + r;
        const float st = sinf((float)t);
        const float ct = cosf((float)t);
        const int row = rowb + r;
#pragma unroll
        for (int s4 = 0; s4 < 4; ++s4) {
            const int cc = s4 * 16 + l16;
            float vq = acc[s4][r] + bq4[s4];
            float pq = __shfl_xor(vq, 1);
            vq = (cc & 1) ? (pq * st + vq * ct) : (vq * ct - pq * st);
            Qw[(size_t)row * HD + cc] = (_Float16)(vq * QSCALE2);
            float vk = acc[4 + s4][r] + bk4[s4];
            float pk = __shfl_xor(vk, 1);
            vk = (cc & 1) ? (pk * st + vk * ct) : (vk * ct - pk * st);
            Kw[(size_t)row * HD + cc] = (_Float16)vk;
        }
    }
#pragma unroll
    for (int s4 = 0; s4 < 4; ++s4) {
        const int cc = s4 * 16 + l16;
        half4 vpack;
#pragma unroll
        for (int r = 0; r < 4; ++r) vpack[r] = (_Float16)(acc[8 + s4][r] + bv4[s4]);
        *(half4*)(Vtw + ((size_t)bidx * HD + cc) * TSEQ + t00) = vpack;
    }
}

// ---------------------------------------------------------------------------
// Kernel D: causal flash attention, j-PARALLEL across waves. Fixed-bias
// softmax makes O and l plain sums -> wave w owns j ≡ w (mod 4), computes the
// FULL 64x64 tile (4 q-strips share every K/V fragment: 72 MFMA / 16 loads),
// partials reduced once through LDS at the end. No running max, no shuffles,
// no in-loop barriers. exp2-based (log2e folded into Q).
// ---------------------------------------------------------------------------
__global__ __launch_bounds__(256) void attn_kernel(
    const _Float16* __restrict__ Qw, const _Float16* __restrict__ Kw,
    const _Float16* __restrict__ Vtw, float* __restrict__ out, int b0)
{
    const int qtile = 7 - blockIdx.x;            // long blocks launch first
    const int bl    = blockIdx.y;
    const int tid   = threadIdx.x;
    const int wave  = tid >> 6;
    const int lane  = tid & 63;
    const int l16   = lane & 15;
    const int quad  = lane >> 4;

    __shared__ __align__(16) _Float16 pbuf[4][16][72];   // 9 KB
    __shared__ __align__(16) float oBuf[4][64][64];      // 64 KB partial O
    __shared__ float lBuf[4][64];                        // 1 KB partial l

    const _Float16* Qb = Qw  + (size_t)bl * TSEQ * HD;
    const _Float16* Kb = Kw  + (size_t)bl * TSEQ * HD;
    const _Float16* Vb = Vtw + (size_t)bl * HD * TSEQ;   // [d][t]

    const int qb = qtile * 64;

    half8 aQ0[4], aQ1[4];
#pragma unroll
    for (int st = 0; st < 4; ++st) {
        const _Float16* qp = Qb + (size_t)(qb + st * 16 + l16) * HD + quad * 8;
        aQ0[st] = *(const half8*)(qp);
        aQ1[st] = *(const half8*)(qp + 32);
    }

    half8 ones;
#pragma unroll
    for (int jj = 0; jj < 8; ++jj) ones[jj] = (_Float16)1.f;

    floatx4 accO[4][4], accL[4];
#pragma unroll
    for (int st = 0; st < 4; ++st) {
#pragma unroll
        for (int s4 = 0; s4 < 4; ++s4)
#pragma unroll
            for (int r = 0; r < 4; ++r) accO[st][s4][r] = 0.f;
#pragma unroll
        for (int r = 0; r < 4; ++r) accL[st][r] = 0.f;
    }

    for (int j = wave; j <= qtile; j += 4) {
        const int kb = j * 64;
        const bool diag = (j == qtile);

        // ---- S^T for all 4 strips, K-fragments shared ----
        floatx4 st4[4][4];                       // [strip][s4]
#pragma unroll
        for (int s4 = 0; s4 < 4; ++s4) {
            const _Float16* kp = Kb + (size_t)(kb + s4 * 16 + l16) * HD + quad * 8;
            half8 bK0 = *(const half8*)(kp);
            half8 bK1 = *(const half8*)(kp + 32);
#pragma unroll
            for (int st = 0; st < 4; ++st) {
                floatx4 z;
#pragma unroll
                for (int r = 0; r < 4; ++r) z[r] = 0.f;
                z = __builtin_amdgcn_mfma_f32_16x16x32_f16(bK0, aQ0[st], z, 0, 0, 0);
                st4[st][s4] = __builtin_amdgcn_mfma_f32_16x16x32_f16(bK1, aQ1[st], z, 0, 0, 0);
            }
        }

        // ---- V fragments (shared across strips), issued before exp ----
        half8 bV0[4], bV1[4];
#pragma unroll
        for (int s4 = 0; s4 < 4; ++s4) {
            const _Float16* vp = Vb + (size_t)(s4 * 16 + l16) * TSEQ + kb + quad * 8;
            bV0[s4] = *(const half8*)(vp);
            bV1[s4] = *(const half8*)(vp + 32);
        }

        // ---- per strip: exp2 + mask -> pbuf -> PV ----
#pragma unroll
        for (int st = 0; st < 4; ++st) {
            const int qrow = qb + st * 16 + l16;
#pragma unroll
            for (int s4 = 0; s4 < 4; ++s4) {
                half4 w;
#pragma unroll
                for (int r = 0; r < 4; ++r) {
                    float p = exp2f(fminf(st4[st][s4][r], SCLAMP) - MBIAS2);
                    if (diag) {
                        const int kcol = kb + s4 * 16 + quad * 4 + r;
                        if (kcol > qrow) p = 0.f;
                    }
                    w[r] = (_Float16)p;
                }
                *(half4*)(&pbuf[wave][l16][s4 * 16 + quad * 4]) = w;
            }
            half8 aP0 = *(const half8*)(&pbuf[wave][l16][quad * 8]);
            half8 aP1 = *(const half8*)(&pbuf[wave][l16][32 + quad * 8]);
#pragma unroll
            for (int s4 = 0; s4 < 4; ++s4) {
                accO[st][s4] = __builtin_amdgcn_mfma_f32_16x16x32_f16(aP0, bV0[s4], accO[st][s4], 0, 0, 0);
                accO[st][s4] = __builtin_amdgcn_mfma_f32_16x16x32_f16(aP1, bV1[s4], accO[st][s4], 0, 0, 0);
            }
            accL[st] = __builtin_amdgcn_mfma_f32_16x16x32_f16(aP0, ones, accL[st], 0, 0, 0);
            accL[st] = __builtin_amdgcn_mfma_f32_16x16x32_f16(aP1, ones, accL[st], 0, 0, 0);
        }
    }

    // ---- cross-wave reduction ----
#pragma unroll
    for (int st = 0; st < 4; ++st) {
#pragma unroll
        for (int s4 = 0; s4 < 4; ++s4)
#pragma unroll
            for (int r = 0; r < 4; ++r)
                oBuf[wave][st * 16 + quad * 4 + r][s4 * 16 + l16] = accO[st][s4][r];
        if (l16 == 0)
#pragma unroll
            for (int r = 0; r < 4; ++r)
                lBuf[wave][st * 16 + quad * 4 + r] = accL[st][r];
    }
    __syncthreads();

    const size_t obase = ((size_t)(b0 + bl) * TSEQ + qb) * HD;
#pragma unroll
    for (int it = 0; it < 16; ++it) {
        const int e   = it * 256 + tid;
        const int row = e >> 6;
        const int col = e & 63;
        const float o = oBuf[0][row][col] + oBuf[1][row][col] +
                        oBuf[2][row][col] + oBuf[3][row][col];
        const float l = lBuf[0][row] + lBuf[1][row] + lBuf[2][row] + lBuf[3][row];
        out[obase + (size_t)row * HD + col] = o / l;
    }
}

// ---------------------------------------------------------------------------
extern "C" void kernel_launch(void* const* d_in, const int* in_sizes, int n_in,
                              void* d_out, int out_size, void* d_ws, size_t ws_size,
                              hipStream_t stream)
{
    char* ws = (char*)d_ws;
    _Float16* Wt = (_Float16*)ws;                           // 147456 B
    char* qkv_base = ws + 147456;

    const size_t per_b = (size_t)3 * TSEQ * HD * sizeof(_Float16);  // 196608 B
    size_t avail = (ws_size > (size_t)147456) ? ws_size - 147456 : per_b;
    int nbc = (int)(avail / per_b);
    if (nbc > NB) nbc = NB;
    if (nbc < 1)  nbc = 1;

    const size_t chunk_elems = (size_t)nbc * TSEQ * HD;
    _Float16* Qw  = (_Float16*)qkv_base;
    _Float16* Kw  = Qw + chunk_elems;
    _Float16* Vtw = Kw + chunk_elems;

    prep_w<<<dim3((3 * CDIM * HD + 255) / 256), dim3(256), 0, stream>>>(
        (const float*)d_in[1], (const float*)d_in[3], (const float*)d_in[5], Wt);

    for (int b0 = 0; b0 < NB; b0 += nbc) {
        const int nb = (NB - b0 < nbc) ? (NB - b0) : nbc;
        qkv_gemm<<<dim3(nb * 8), dim3(256), 0, stream>>>(
            (const float*)d_in[0], Wt, (const float*)d_in[2], (const float*)d_in[4],
            (const float*)d_in[6], Qw, Kw, Vtw, b0);
        attn_kernel<<<dim3(8, nb), dim3(256), 0, stream>>>(
            Qw, Kw, Vtw, (float*)d_out, b0);
    }
}

// Round 8
// 216.428 us; speedup vs baseline: 1.0715x; 1.0715x over previous
//
#include <hip/hip_runtime.h>

#define TSEQ 512
#define NB   128
#define CDIM 384
#define HD   64
// 384^-0.5 * log2(e): Q pre-scaled so attention uses exp2 directly
#define QSCALE2 0.07362222569f
#define MBIAS2  11.541560327f          // 8 * log2(e); exact offset, cancels in O/l
#define SCLAMP  26.0f                  // 18 * log2(e)

typedef _Float16 half8  __attribute__((ext_vector_type(8)));
typedef _Float16 half4  __attribute__((ext_vector_type(4)));
typedef float    floatx4 __attribute__((ext_vector_type(4)));

typedef __attribute__((address_space(3))) unsigned int lds_u32;
typedef const __attribute__((address_space(1))) unsigned int g_u32;

__device__ __forceinline__ void load_lds16(const void* g, void* l) {
    __builtin_amdgcn_global_load_lds((g_u32*)g, (lds_u32*)l, 16, 0, 0);
}

// ---------------------------------------------------------------------------
// Kernel B: repack the three 384x64 fp32 weight matrices into Wt[mat*64+n][k]
// fp16 so GEMM B loads are contiguous 16B along k.
// ---------------------------------------------------------------------------
__global__ void prep_w(const float* __restrict__ wq, const float* __restrict__ wk,
                       const float* __restrict__ wv, _Float16* __restrict__ Wt)
{
    int i = blockIdx.x * 256 + threadIdx.x;
    const int per = CDIM * HD;               // 24576
    if (i >= 3 * per) return;
    int mat = i / per;
    int rem = i - mat * per;
    int k = rem / HD;
    int n = rem - k * HD;
    const float* w = (mat == 0) ? wq : ((mat == 1) ? wk : wv);
    Wt[((size_t)mat * HD + n) * CDIM + k] = (_Float16)w[rem];
}

// ---------------------------------------------------------------------------
// Kernel C: fused QKV projection, global_load_lds pipeline, BK=96.
// R7 lesson: dbuf is neutral (compute/chunk ~200 cyc << DMA ~2000 cyc);
// time tracks CHUNK COUNT. So: 4 chunks of K=96 (was 6 of 64), single
// buffer, 60 KB LDS -> 2 blocks/CU. Per chunk: x 24 KB (6 DMA/wave) +
// W 36 KB (9 DMA/wave); compute 3 K32-steps x 12 MFMA.
// mfma_f32_16x16x32_f16: A[m=lane&15][k=quad*8+j], B[k=..][n=lane&15],
// C/D[row=quad*4+reg][col=lane&15]. RoPE (fres==1 -> angle=t) via shfl_xor 1.
// ---------------------------------------------------------------------------
__global__ __launch_bounds__(256) void qkv_gemm(
    const float* __restrict__ x, const _Float16* __restrict__ Wt,
    const float* __restrict__ bq, const float* __restrict__ bk,
    const float* __restrict__ bv,
    _Float16* __restrict__ Qw, _Float16* __restrict__ Kw,
    _Float16* __restrict__ Vtw, int b0)
{
    __shared__ __align__(16) float    xs[12 * 64 * 8];    // 24 KB [kblk][m][kin]
    __shared__ __align__(16) _Float16 wsb[12 * 192 * 8];  // 36 KB [kblk][n][kin]

    const int tid  = threadIdx.x;
    const int wave = tid >> 6;
    const int lane = tid & 63;
    const int l16  = lane & 15;
    const int quad = lane >> 4;

    const int row0 = blockIdx.x * 64;
    const size_t rowg = (size_t)b0 * TSEQ + row0;

    floatx4 acc[12];
#pragma unroll
    for (int i = 0; i < 12; ++i)
#pragma unroll
        for (int r = 0; r < 4; ++r) acc[i][r] = 0.f;

    for (int c = 0; c < 4; ++c) {
        const int kk0 = c * 96;

        // ---- stage x: 24 KB, 6 DMA/wave ----
#pragma unroll
        for (int i = 0; i < 6; ++i) {
            const int I    = wave * 6 + i;
            const int cell = I * 32 + (lane >> 1);       // kblk*64 + m
            const int kblk = cell >> 6;
            const int m    = cell & 63;
            const int kin0 = (lane & 1) * 4;
            const float* src = x + (rowg + m) * CDIM + kk0 + kblk * 8 + kin0;
            load_lds16(src, (char*)xs + I * 1024);
        }
        // ---- stage W: 36 KB, 9 DMA/wave ----
#pragma unroll
        for (int i = 0; i < 9; ++i) {
            const int I2   = wave * 9 + i;
            const int c2   = I2 * 64 + lane;             // kblk*192 + n
            const int kblk = c2 / 192;
            const int n    = c2 - kblk * 192;
            const _Float16* src = Wt + (size_t)n * CDIM + kk0 + kblk * 8;
            load_lds16(src, (char*)wsb + I2 * 1024);
        }
        __syncthreads();                                  // drain DMA

        // ---- compute: 3 K32-steps, 12 MFMA each ----
#pragma unroll
        for (int kb2 = 0; kb2 < 3; ++kb2) {
            const int kblk = kb2 * 4 + quad;
            const float* ap = xs + ((size_t)kblk * 64 + wave * 16 + l16) * 8;
            floatx4 a0 = *(const floatx4*)ap;
            floatx4 a1 = *(const floatx4*)(ap + 4);
            half8 a;
#pragma unroll
            for (int jj = 0; jj < 8; ++jj)
                a[jj] = (_Float16)(jj < 4 ? a0[jj] : a1[jj - 4]);
            const _Float16* bp = wsb + ((size_t)kblk * 192 + l16) * 8;
#pragma unroll
            for (int i = 0; i < 12; ++i) {
                half8 bb = *(const half8*)(bp + i * 128);
                acc[i] = __builtin_amdgcn_mfma_f32_16x16x32_f16(a, bb, acc[i], 0, 0, 0);
            }
        }
        if (c < 3) __syncthreads();                       // buffer reuse guard
    }

    // ---- epilogue: bias + RoPE; Q/K row-major, V transposed (b,d,t) ----
    float bq4[4], bk4[4], bv4[4];
#pragma unroll
    for (int s4 = 0; s4 < 4; ++s4) {
        const int cc = s4 * 16 + l16;
        bq4[s4] = bq[cc]; bk4[s4] = bk[cc]; bv4[s4] = bv[cc];
    }
    const int t00  = (row0 & (TSEQ - 1)) + wave * 16 + quad * 4;
    const int bidx = row0 >> 9;
    const int rowb = row0 + wave * 16 + quad * 4;

#pragma unroll
    for (int r = 0; r < 4; ++r) {
        const int t = t00 + r;
        const float st = sinf((float)t);
        const float ct = cosf((float)t);
        const int row = rowb + r;
#pragma unroll
        for (int s4 = 0; s4 < 4; ++s4) {
            const int cc = s4 * 16 + l16;
            float vq = acc[s4][r] + bq4[s4];
            float pq = __shfl_xor(vq, 1);
            vq = (cc & 1) ? (pq * st + vq * ct) : (vq * ct - pq * st);
            Qw[(size_t)row * HD + cc] = (_Float16)(vq * QSCALE2);
            float vk = acc[4 + s4][r] + bk4[s4];
            float pk = __shfl_xor(vk, 1);
            vk = (cc & 1) ? (pk * st + vk * ct) : (vk * ct - pk * st);
            Kw[(size_t)row * HD + cc] = (_Float16)vk;
        }
    }
#pragma unroll
    for (int s4 = 0; s4 < 4; ++s4) {
        const int cc = s4 * 16 + l16;
        half4 vpack;
#pragma unroll
        for (int r = 0; r < 4; ++r) vpack[r] = (_Float16)(acc[8 + s4][r] + bv4[s4]);
        *(half4*)(Vtw + ((size_t)bidx * HD + cc) * TSEQ + t00) = vpack;
    }
}

// ---------------------------------------------------------------------------
// Kernel D: causal flash attention (R6 design — best measured). TWO q-strips
// per wave (rows qA and qA+64 share every K/V fragment -> 36 MFMA per 16
// loads). Fixed softmax offset (exact — cancels in O/l). Row sums via
// ones-MFMA. S computed transposed (operand swap) -> P to LDS as 4x
// ds_write_b64, wave-private pbuf, no barriers, no shuffles. exp2-based.
// Long diagonal blocks launch first.
// ---------------------------------------------------------------------------
__global__ __launch_bounds__(256) void attn_kernel(
    const _Float16* __restrict__ Qw, const _Float16* __restrict__ Kw,
    const _Float16* __restrict__ Vtw, float* __restrict__ out, int b0)
{
    const int qt   = 3 - blockIdx.x;             // longest (qt=3) first
    const int bl   = blockIdx.y;
    const int tid  = threadIdx.x;
    const int wave = tid >> 6;
    const int lane = tid & 63;
    const int l16  = lane & 15;
    const int quad = lane >> 4;

    __shared__ __align__(16) _Float16 pbuf[4][16][72];

    const _Float16* Qb = Qw  + (size_t)bl * TSEQ * HD;
    const _Float16* Kb = Kw  + (size_t)bl * TSEQ * HD;
    const _Float16* Vb = Vtw + (size_t)bl * HD * TSEQ;   // [d][t]

    const int qA = qt * 128 + wave * 16;
    const int qB = qA + 64;
    const int jd = 2 * qt;                       // strip A diagonal tile

    half8 aQA0 = *(const half8*)(Qb + (size_t)(qA + l16) * HD + quad * 8);
    half8 aQA1 = *(const half8*)(Qb + (size_t)(qA + l16) * HD + 32 + quad * 8);
    half8 aQB0 = *(const half8*)(Qb + (size_t)(qB + l16) * HD + quad * 8);
    half8 aQB1 = *(const half8*)(Qb + (size_t)(qB + l16) * HD + 32 + quad * 8);

    half8 ones;
#pragma unroll
    for (int jj = 0; jj < 8; ++jj) ones[jj] = (_Float16)1.f;

    floatx4 accO[8], accL[2];
#pragma unroll
    for (int i = 0; i < 8; ++i)
#pragma unroll
        for (int r = 0; r < 4; ++r) accO[i][r] = 0.f;
#pragma unroll
    for (int s = 0; s < 2; ++s)
#pragma unroll
        for (int r = 0; r < 4; ++r) accL[s][r] = 0.f;

    for (int j = 0; j <= jd + 1; ++j) {
        const int kb = j * 64;

        half8 bK0[4], bK1[4], bV0[4], bV1[4];
#pragma unroll
        for (int s4 = 0; s4 < 4; ++s4) {
            const _Float16* kp = Kb + (size_t)(kb + s4 * 16 + l16) * HD + quad * 8;
            bK0[s4] = *(const half8*)(kp);
            bK1[s4] = *(const half8*)(kp + 32);
            const _Float16* vp = Vb + (size_t)(s4 * 16 + l16) * TSEQ + kb + quad * 8;
            bV0[s4] = *(const half8*)(vp);
            bV1[s4] = *(const half8*)(vp + 32);
        }

        // ================= strip A (skip on its dead last iter) ===========
        if (j <= jd) {
            floatx4 st4[4];
#pragma unroll
            for (int s4 = 0; s4 < 4; ++s4) {
#pragma unroll
                for (int r = 0; r < 4; ++r) st4[s4][r] = 0.f;
                st4[s4] = __builtin_amdgcn_mfma_f32_16x16x32_f16(bK0[s4], aQA0, st4[s4], 0, 0, 0);
                st4[s4] = __builtin_amdgcn_mfma_f32_16x16x32_f16(bK1[s4], aQA1, st4[s4], 0, 0, 0);
            }
            const int qrow = qA + l16;
#pragma unroll
            for (int s4 = 0; s4 < 4; ++s4) {
                half4 w;
#pragma unroll
                for (int r = 0; r < 4; ++r) {
                    float p = exp2f(fminf(st4[s4][r], SCLAMP) - MBIAS2);
                    if (j == jd) {
                        const int kcol = kb + s4 * 16 + quad * 4 + r;
                        if (kcol > qrow) p = 0.f;
                    }
                    w[r] = (_Float16)p;
                }
                *(half4*)(&pbuf[wave][l16][s4 * 16 + quad * 4]) = w;
            }
            half8 aP0 = *(const half8*)(&pbuf[wave][l16][quad * 8]);
            half8 aP1 = *(const half8*)(&pbuf[wave][l16][32 + quad * 8]);
#pragma unroll
            for (int s4 = 0; s4 < 4; ++s4) {
                accO[s4] = __builtin_amdgcn_mfma_f32_16x16x32_f16(aP0, bV0[s4], accO[s4], 0, 0, 0);
                accO[s4] = __builtin_amdgcn_mfma_f32_16x16x32_f16(aP1, bV1[s4], accO[s4], 0, 0, 0);
            }
            accL[0] = __builtin_amdgcn_mfma_f32_16x16x32_f16(aP0, ones, accL[0], 0, 0, 0);
            accL[0] = __builtin_amdgcn_mfma_f32_16x16x32_f16(aP1, ones, accL[0], 0, 0, 0);
        }

        // ================= strip B ========================================
        {
            floatx4 st4[4];
#pragma unroll
            for (int s4 = 0; s4 < 4; ++s4) {
#pragma unroll
                for (int r = 0; r < 4; ++r) st4[s4][r] = 0.f;
                st4[s4] = __builtin_amdgcn_mfma_f32_16x16x32_f16(bK0[s4], aQB0, st4[s4], 0, 0, 0);
                st4[s4] = __builtin_amdgcn_mfma_f32_16x16x32_f16(bK1[s4], aQB1, st4[s4], 0, 0, 0);
            }
            const int qrow = qB + l16;
#pragma unroll
            for (int s4 = 0; s4 < 4; ++s4) {
                half4 w;
#pragma unroll
                for (int r = 0; r < 4; ++r) {
                    float p = exp2f(fminf(st4[s4][r], SCLAMP) - MBIAS2);
                    if (j == jd + 1) {
                        const int kcol = kb + s4 * 16 + quad * 4 + r;
                        if (kcol > qrow) p = 0.f;
                    }
                    w[r] = (_Float16)p;
                }
                *(half4*)(&pbuf[wave][l16][s4 * 16 + quad * 4]) = w;
            }
            half8 aP0 = *(const half8*)(&pbuf[wave][l16][quad * 8]);
            half8 aP1 = *(const half8*)(&pbuf[wave][l16][32 + quad * 8]);
#pragma unroll
            for (int s4 = 0; s4 < 4; ++s4) {
                accO[4 + s4] = __builtin_amdgcn_mfma_f32_16x16x32_f16(aP0, bV0[s4], accO[4 + s4], 0, 0, 0);
                accO[4 + s4] = __builtin_amdgcn_mfma_f32_16x16x32_f16(aP1, bV1[s4], accO[4 + s4], 0, 0, 0);
            }
            accL[1] = __builtin_amdgcn_mfma_f32_16x16x32_f16(aP0, ones, accL[1], 0, 0, 0);
            accL[1] = __builtin_amdgcn_mfma_f32_16x16x32_f16(aP1, ones, accL[1], 0, 0, 0);
        }
    }

    // ---- epilogue ----
#pragma unroll
    for (int s = 0; s < 2; ++s) {
        const int qbase = (s == 0) ? qA : qB;
        float inv[4];
#pragma unroll
        for (int r = 0; r < 4; ++r) inv[r] = 1.f / accL[s][r];
#pragma unroll
        for (int s4 = 0; s4 < 4; ++s4) {
            const int dcol = s4 * 16 + l16;
#pragma unroll
            for (int r = 0; r < 4; ++r) {
                const int qr = qbase + quad * 4 + r;
                out[((size_t)(b0 + bl) * TSEQ + qr) * HD + dcol] =
                    accO[s * 4 + s4][r] * inv[r];
            }
        }
    }
}

// ---------------------------------------------------------------------------
extern "C" void kernel_launch(void* const* d_in, const int* in_sizes, int n_in,
                              void* d_out, int out_size, void* d_ws, size_t ws_size,
                              hipStream_t stream)
{
    char* ws = (char*)d_ws;
    _Float16* Wt = (_Float16*)ws;                           // 147456 B
    char* qkv_base = ws + 147456;

    const size_t per_b = (size_t)3 * TSEQ * HD * sizeof(_Float16);  // 196608 B
    size_t avail = (ws_size > (size_t)147456) ? ws_size - 147456 : per_b;
    int nbc = (int)(avail / per_b);
    if (nbc > NB) nbc = NB;
    if (nbc < 1)  nbc = 1;

    const size_t chunk_elems = (size_t)nbc * TSEQ * HD;
    _Float16* Qw  = (_Float16*)qkv_base;
    _Float16* Kw  = Qw + chunk_elems;
    _Float16* Vtw = Kw + chunk_elems;

    prep_w<<<dim3((3 * CDIM * HD + 255) / 256), dim3(256), 0, stream>>>(
        (const float*)d_in[1], (const float*)d_in[3], (const float*)d_in[5], Wt);

    for (int b0 = 0; b0 < NB; b0 += nbc) {
        const int nb = (NB - b0 < nbc) ? (NB - b0) : nbc;
        qkv_gemm<<<dim3(nb * 8), dim3(256), 0, stream>>>(
            (const float*)d_in[0], Wt, (const float*)d_in[2], (const float*)d_in[4],
            (const float*)d_in[6], Qw, Kw, Vtw, b0);
        attn_kernel<<<dim3(4, nb), dim3(256), 0, stream>>>(
            Qw, Kw, Vtw, (float*)d_out, b0);
    }
}